// Round 1
// baseline (459.295 us; speedup 1.0000x reference)
//
#include <hip/hip_runtime.h>
#include <hip/hip_bf16.h>
#include <math.h>

// Problem constants (fixed by the reference's setup_inputs)
constexpr int N_  = 2;
constexpr int E_  = 16;
constexpr int C_  = 32;
constexpr int V_  = 48 * 160 * 160;   // 1,228,800 voxels per batch
constexpr int V4_ = V_ / 4;           // 307,200 float4 groups
constexpr int BLK = 256;
constexpr int NBLK = V4_ / BLK;       // 1200 (exact)

constexpr float DELTA_VAR  = 0.5f;
constexpr float DELTA_DIST = 2.0f;
constexpr float GAMMA      = 0.001f;

// Workspace layout (floats):
//   [0, N*C*E)              per-cluster sums        [n][c][e]
//   [N*C*E, +N*C)           per-cluster counts      [n][c]
//   [N*C*E+N*C, +N*C)       per-cluster hinge sums  [n][c]
constexpr int WS_SUMS  = 0;
constexpr int WS_CNT   = N_ * C_ * E_;          // 1024
constexpr int WS_HINGE = WS_CNT + N_ * C_;      // 1088
constexpr int WS_FLOATS = WS_HINGE + N_ * C_;   // 1152

// ---------------------------------------------------------------------------
// Pass 1: per-cluster counts and per-dim sums (hierarchical: LDS -> global)
// grid = (NBLK, N), block = 256
// ---------------------------------------------------------------------------
__global__ __launch_bounds__(BLK) void pass1_sums(
    const float4* __restrict__ input,   // [N][E][V4]
    const int4*   __restrict__ target,  // [N][V4]
    float* __restrict__ ws)
{
    // [c][0..15] = sums, [c][16] = count; stride 17 (odd) -> bank permutation
    __shared__ float s_acc[C_ * 17];
    for (int i = threadIdx.x; i < C_ * 17; i += BLK) s_acc[i] = 0.0f;
    __syncthreads();

    const int n   = blockIdx.y;
    const int idx = blockIdx.x * BLK + threadIdx.x;   // grid covers V4 exactly

    const int4 l4 = target[n * V4_ + idx];
    const int lab0 = l4.x * 17, lab1 = l4.y * 17, lab2 = l4.z * 17, lab3 = l4.w * 17;

    #pragma unroll
    for (int e = 0; e < E_; ++e) {
        const float4 x = input[(n * E_ + e) * V4_ + idx];
        atomicAdd(&s_acc[lab0 + e], x.x);
        atomicAdd(&s_acc[lab1 + e], x.y);
        atomicAdd(&s_acc[lab2 + e], x.z);
        atomicAdd(&s_acc[lab3 + e], x.w);
    }
    atomicAdd(&s_acc[lab0 + 16], 1.0f);
    atomicAdd(&s_acc[lab1 + 16], 1.0f);
    atomicAdd(&s_acc[lab2 + 16], 1.0f);
    atomicAdd(&s_acc[lab3 + 16], 1.0f);
    __syncthreads();

    float* gsum = ws + WS_SUMS;
    float* gcnt = ws + WS_CNT;
    for (int i = threadIdx.x; i < C_ * 17; i += BLK) {
        const int c = i / 17, r = i - c * 17;
        const float v = s_acc[i];
        if (r < E_) atomicAdd(&gsum[(n * C_ + c) * E_ + r], v);
        else        atomicAdd(&gcnt[n * C_ + c], v);
    }
}

// ---------------------------------------------------------------------------
// Pass 2: per-voxel hinge distance to own cluster mean, segment-summed
// grid = (NBLK, N), block = 256
// ---------------------------------------------------------------------------
__global__ __launch_bounds__(BLK) void pass2_hinge(
    const float4* __restrict__ input,
    const int4*   __restrict__ target,
    float* __restrict__ ws)
{
    __shared__ float s_mean[C_ * 17];
    __shared__ float s_h[C_];

    const float* gsum = ws + WS_SUMS;
    const float* gcnt = ws + WS_CNT;
    float*       ghin = ws + WS_HINGE;

    const int n = blockIdx.y;
    for (int i = threadIdx.x; i < C_ * E_; i += BLK) {
        const int c = i >> 4, e = i & 15;
        s_mean[c * 17 + e] = gsum[(n * C_ + c) * E_ + e] / gcnt[n * C_ + c];
    }
    if (threadIdx.x < C_) s_h[threadIdx.x] = 0.0f;
    __syncthreads();

    const int idx = blockIdx.x * BLK + threadIdx.x;
    const int4 l4 = target[n * V4_ + idx];
    const int lab0 = l4.x * 17, lab1 = l4.y * 17, lab2 = l4.z * 17, lab3 = l4.w * 17;

    float d0 = 0.f, d1 = 0.f, d2 = 0.f, d3 = 0.f;
    #pragma unroll
    for (int e = 0; e < E_; ++e) {
        const float4 x = input[(n * E_ + e) * V4_ + idx];
        const float m0 = s_mean[lab0 + e];
        const float m1 = s_mean[lab1 + e];
        const float m2 = s_mean[lab2 + e];
        const float m3 = s_mean[lab3 + e];
        d0 += (x.x - m0) * (x.x - m0);
        d1 += (x.y - m1) * (x.y - m1);
        d2 += (x.z - m2) * (x.z - m2);
        d3 += (x.w - m3) * (x.w - m3);
    }
    // _safe_norm: zero-safe, then hinge^2
    const float n0 = d0 > 0.f ? sqrtf(d0) : 0.f;
    const float n1 = d1 > 0.f ? sqrtf(d1) : 0.f;
    const float n2 = d2 > 0.f ? sqrtf(d2) : 0.f;
    const float n3 = d3 > 0.f ? sqrtf(d3) : 0.f;
    const float h0 = fmaxf(n0 - DELTA_VAR, 0.f);
    const float h1 = fmaxf(n1 - DELTA_VAR, 0.f);
    const float h2 = fmaxf(n2 - DELTA_VAR, 0.f);
    const float h3 = fmaxf(n3 - DELTA_VAR, 0.f);
    atomicAdd(&s_h[l4.x], h0 * h0);
    atomicAdd(&s_h[l4.y], h1 * h1);
    atomicAdd(&s_h[l4.z], h2 * h2);
    atomicAdd(&s_h[l4.w], h3 * h3);
    __syncthreads();

    if (threadIdx.x < C_) atomicAdd(&ghin[n * C_ + threadIdx.x], s_h[threadIdx.x]);
}

// ---------------------------------------------------------------------------
// Finalize: means -> variance + pairwise distance + regularizer -> scalar
// single block of 256
// ---------------------------------------------------------------------------
__global__ __launch_bounds__(BLK) void finalize(
    const float* __restrict__ ws, float* __restrict__ out)
{
    __shared__ float s_mean[C_ * 17];
    __shared__ float s_red;
    __shared__ float s_total;

    const float* gsum = ws + WS_SUMS;
    const float* gcnt = ws + WS_CNT;
    const float* ghin = ws + WS_HINGE;

    if (threadIdx.x == 0) s_total = 0.0f;

    for (int n = 0; n < N_; ++n) {
        __syncthreads();
        for (int i = threadIdx.x; i < C_ * E_; i += BLK) {
            const int c = i >> 4, e = i & 15;
            s_mean[c * 17 + e] = gsum[(n * C_ + c) * E_ + e] / gcnt[n * C_ + c];
        }
        if (threadIdx.x == 0) s_red = 0.0f;
        __syncthreads();

        float local = 0.0f;

        // variance term + regularizer (one thread per cluster)
        if (threadIdx.x < C_) {
            const int c = threadIdx.x;
            local += ghin[n * C_ + c] / gcnt[n * C_ + c] / (float)C_;  // ALPHA=1
            float d2 = 0.f;
            #pragma unroll
            for (int e = 0; e < E_; ++e) {
                const float m = s_mean[c * 17 + e];
                d2 += m * m;
            }
            const float nm = d2 > 0.f ? sqrtf(d2) : 0.f;
            local += GAMMA * nm / (float)C_;
        }

        // pairwise cluster-mean repulsion
        for (int t = threadIdx.x; t < C_ * C_; t += BLK) {
            const int i = t >> 5, j = t & 31;
            if (i != j) {
                float d2 = 0.f;
                #pragma unroll
                for (int e = 0; e < E_; ++e) {
                    const float diff = s_mean[i * 17 + e] - s_mean[j * 17 + e];
                    d2 += diff * diff;
                }
                const float d = d2 > 0.f ? sqrtf(d2) : 0.f;
                const float h = fmaxf(2.0f * DELTA_DIST - d, 0.f);
                local += (h * h) / (float)(C_ * (C_ - 1));             // BETA=1
            }
        }

        atomicAdd(&s_red, local);
        __syncthreads();
        if (threadIdx.x == 0) s_total += s_red;
    }
    __syncthreads();
    if (threadIdx.x == 0) out[0] = s_total / (float)N_;
}

// ---------------------------------------------------------------------------
extern "C" void kernel_launch(void* const* d_in, const int* in_sizes, int n_in,
                              void* d_out, int out_size, void* d_ws, size_t ws_size,
                              hipStream_t stream) {
    const float4* input  = (const float4*)d_in[0];
    const int4*   target = (const int4*)d_in[1];
    float* ws  = (float*)d_ws;
    float* out = (float*)d_out;

    hipMemsetAsync(d_ws, 0, WS_FLOATS * sizeof(float), stream);

    dim3 grid(NBLK, N_);
    pass1_sums<<<grid, BLK, 0, stream>>>(input, target, ws);
    pass2_hinge<<<grid, BLK, 0, stream>>>(input, target, ws);
    finalize<<<1, BLK, 0, stream>>>(ws, out);
}

// Round 2
// 452.380 us; speedup vs baseline: 1.0153x; 1.0153x over previous
//
#include <hip/hip_runtime.h>
#include <hip/hip_bf16.h>
#include <math.h>

// Problem constants (fixed by the reference's setup_inputs)
constexpr int N_  = 2;
constexpr int E_  = 16;
constexpr int C_  = 32;
constexpr int V_  = 48 * 160 * 160;   // 1,228,800 voxels per batch
constexpr int V4_ = V_ / 4;           // 307,200 float4 groups
constexpr int BLK = 256;
constexpr int NBLK = V4_ / BLK;       // 1200 (exact)

constexpr float DELTA_VAR  = 0.5f;
constexpr float DELTA_DIST = 2.0f;
constexpr float GAMMA      = 0.001f;

// Workspace layout (floats):
constexpr int WS_SUMS  = 0;                     // [N][C][E]
constexpr int WS_CNT   = N_ * C_ * E_;          // 1024  [N][C]
constexpr int WS_HINGE = WS_CNT + N_ * C_;      // 1088  [N][C]
constexpr int WS_FLOATS = WS_HINGE + N_ * C_;   // 1152

// ---------------------------------------------------------------------------
// Pass 1: per-cluster counts and per-dim sums (hierarchical: LDS -> global)
// grid = (NBLK, N), block = 256
// unsafeAtomicAdd: native ds_add_f32 / global_atomic_add_f32 (no CAS loop)
// ---------------------------------------------------------------------------
__global__ __launch_bounds__(BLK) void pass1_sums(
    const float4* __restrict__ input,   // [N][E][V4]
    const int4*   __restrict__ target,  // [N][V4]
    float* __restrict__ ws)
{
    // [c][0..15] = sums, [c][16] = count; stride 17 (odd) -> bank permutation
    __shared__ float s_acc[C_ * 17];
    for (int i = threadIdx.x; i < C_ * 17; i += BLK) s_acc[i] = 0.0f;
    __syncthreads();

    const int n   = blockIdx.y;
    const int idx = blockIdx.x * BLK + threadIdx.x;   // grid covers V4 exactly

    const int4 l4 = target[n * V4_ + idx];
    const int lab0 = l4.x * 17, lab1 = l4.y * 17, lab2 = l4.z * 17, lab3 = l4.w * 17;

    // two chunks of 8 float4 loads in flight each (keeps VGPR moderate)
    #pragma unroll
    for (int half = 0; half < 2; ++half) {
        float4 x[8];
        #pragma unroll
        for (int e = 0; e < 8; ++e)
            x[e] = input[(n * E_ + half * 8 + e) * V4_ + idx];
        #pragma unroll
        for (int e = 0; e < 8; ++e) {
            const int eo = half * 8 + e;
            unsafeAtomicAdd(&s_acc[lab0 + eo], x[e].x);
            unsafeAtomicAdd(&s_acc[lab1 + eo], x[e].y);
            unsafeAtomicAdd(&s_acc[lab2 + eo], x[e].z);
            unsafeAtomicAdd(&s_acc[lab3 + eo], x[e].w);
        }
    }
    unsafeAtomicAdd(&s_acc[lab0 + 16], 1.0f);
    unsafeAtomicAdd(&s_acc[lab1 + 16], 1.0f);
    unsafeAtomicAdd(&s_acc[lab2 + 16], 1.0f);
    unsafeAtomicAdd(&s_acc[lab3 + 16], 1.0f);
    __syncthreads();

    float* gsum = ws + WS_SUMS;
    float* gcnt = ws + WS_CNT;
    for (int i = threadIdx.x; i < C_ * 17; i += BLK) {
        const int c = i / 17, r = i - c * 17;
        const float v = s_acc[i];
        if (r < E_) unsafeAtomicAdd(&gsum[(n * C_ + c) * E_ + r], v);
        else        unsafeAtomicAdd(&gcnt[n * C_ + c], v);
    }
}

// ---------------------------------------------------------------------------
// Pass 2: per-voxel hinge distance to own cluster mean, segment-summed
// grid = (NBLK, N), block = 256
// ---------------------------------------------------------------------------
__global__ __launch_bounds__(BLK) void pass2_hinge(
    const float4* __restrict__ input,
    const int4*   __restrict__ target,
    float* __restrict__ ws)
{
    __shared__ float s_mean[C_ * 17];
    __shared__ float s_h[C_];

    const float* gsum = ws + WS_SUMS;
    const float* gcnt = ws + WS_CNT;
    float*       ghin = ws + WS_HINGE;

    const int n = blockIdx.y;
    for (int i = threadIdx.x; i < C_ * E_; i += BLK) {
        const int c = i >> 4, e = i & 15;
        s_mean[c * 17 + e] = gsum[(n * C_ + c) * E_ + e] / gcnt[n * C_ + c];
    }
    if (threadIdx.x < C_) s_h[threadIdx.x] = 0.0f;
    __syncthreads();

    const int idx = blockIdx.x * BLK + threadIdx.x;
    const int4 l4 = target[n * V4_ + idx];
    const int lab0 = l4.x * 17, lab1 = l4.y * 17, lab2 = l4.z * 17, lab3 = l4.w * 17;

    float d0 = 0.f, d1 = 0.f, d2 = 0.f, d3 = 0.f;
    #pragma unroll
    for (int half = 0; half < 2; ++half) {
        float4 x[8];
        #pragma unroll
        for (int e = 0; e < 8; ++e)
            x[e] = input[(n * E_ + half * 8 + e) * V4_ + idx];
        #pragma unroll
        for (int e = 0; e < 8; ++e) {
            const int eo = half * 8 + e;
            const float m0 = s_mean[lab0 + eo];
            const float m1 = s_mean[lab1 + eo];
            const float m2 = s_mean[lab2 + eo];
            const float m3 = s_mean[lab3 + eo];
            d0 += (x[e].x - m0) * (x[e].x - m0);
            d1 += (x[e].y - m1) * (x[e].y - m1);
            d2 += (x[e].z - m2) * (x[e].z - m2);
            d3 += (x[e].w - m3) * (x[e].w - m3);
        }
    }
    // _safe_norm: zero-safe, then hinge^2
    const float n0 = d0 > 0.f ? sqrtf(d0) : 0.f;
    const float n1 = d1 > 0.f ? sqrtf(d1) : 0.f;
    const float n2 = d2 > 0.f ? sqrtf(d2) : 0.f;
    const float n3 = d3 > 0.f ? sqrtf(d3) : 0.f;
    const float h0 = fmaxf(n0 - DELTA_VAR, 0.f);
    const float h1 = fmaxf(n1 - DELTA_VAR, 0.f);
    const float h2 = fmaxf(n2 - DELTA_VAR, 0.f);
    const float h3 = fmaxf(n3 - DELTA_VAR, 0.f);
    unsafeAtomicAdd(&s_h[l4.x], h0 * h0);
    unsafeAtomicAdd(&s_h[l4.y], h1 * h1);
    unsafeAtomicAdd(&s_h[l4.z], h2 * h2);
    unsafeAtomicAdd(&s_h[l4.w], h3 * h3);
    __syncthreads();

    if (threadIdx.x < C_) unsafeAtomicAdd(&ghin[n * C_ + threadIdx.x], s_h[threadIdx.x]);
}

// ---------------------------------------------------------------------------
// Finalize: means -> variance + pairwise distance + regularizer -> scalar
// single block of 256
// ---------------------------------------------------------------------------
__global__ __launch_bounds__(BLK) void finalize(
    const float* __restrict__ ws, float* __restrict__ out)
{
    __shared__ float s_mean[C_ * 17];
    __shared__ float s_red;
    __shared__ float s_total;

    const float* gsum = ws + WS_SUMS;
    const float* gcnt = ws + WS_CNT;
    const float* ghin = ws + WS_HINGE;

    if (threadIdx.x == 0) s_total = 0.0f;

    for (int n = 0; n < N_; ++n) {
        __syncthreads();
        for (int i = threadIdx.x; i < C_ * E_; i += BLK) {
            const int c = i >> 4, e = i & 15;
            s_mean[c * 17 + e] = gsum[(n * C_ + c) * E_ + e] / gcnt[n * C_ + c];
        }
        if (threadIdx.x == 0) s_red = 0.0f;
        __syncthreads();

        float local = 0.0f;

        // variance term + regularizer (one thread per cluster)
        if (threadIdx.x < C_) {
            const int c = threadIdx.x;
            local += ghin[n * C_ + c] / gcnt[n * C_ + c] / (float)C_;  // ALPHA=1
            float d2 = 0.f;
            #pragma unroll
            for (int e = 0; e < E_; ++e) {
                const float m = s_mean[c * 17 + e];
                d2 += m * m;
            }
            const float nm = d2 > 0.f ? sqrtf(d2) : 0.f;
            local += GAMMA * nm / (float)C_;
        }

        // pairwise cluster-mean repulsion
        for (int t = threadIdx.x; t < C_ * C_; t += BLK) {
            const int i = t >> 5, j = t & 31;
            if (i != j) {
                float d2 = 0.f;
                #pragma unroll
                for (int e = 0; e < E_; ++e) {
                    const float diff = s_mean[i * 17 + e] - s_mean[j * 17 + e];
                    d2 += diff * diff;
                }
                const float d = d2 > 0.f ? sqrtf(d2) : 0.f;
                const float h = fmaxf(2.0f * DELTA_DIST - d, 0.f);
                local += (h * h) / (float)(C_ * (C_ - 1));             // BETA=1
            }
        }

        unsafeAtomicAdd(&s_red, local);
        __syncthreads();
        if (threadIdx.x == 0) s_total += s_red;
    }
    __syncthreads();
    if (threadIdx.x == 0) out[0] = s_total / (float)N_;
}

// ---------------------------------------------------------------------------
extern "C" void kernel_launch(void* const* d_in, const int* in_sizes, int n_in,
                              void* d_out, int out_size, void* d_ws, size_t ws_size,
                              hipStream_t stream) {
    const float4* input  = (const float4*)d_in[0];
    const int4*   target = (const int4*)d_in[1];
    float* ws  = (float*)d_ws;
    float* out = (float*)d_out;

    hipMemsetAsync(d_ws, 0, WS_FLOATS * sizeof(float), stream);

    dim3 grid(NBLK, N_);
    pass1_sums<<<grid, BLK, 0, stream>>>(input, target, ws);
    pass2_hinge<<<grid, BLK, 0, stream>>>(input, target, ws);
    finalize<<<1, BLK, 0, stream>>>(ws, out);
}